// Round 17
// baseline (639.152 us; speedup 1.0000x reference)
//
#include <hip/hip_runtime.h>

#define D_FEAT 64
#define SUBN 128            // nodes per bin
#define SUBN_SHIFT 7
#define NBINS_MAX 1024
#define CH 4096             // edges per chunk (LDS edge cache = 4096*6B = 24 KB)
#define SCAN_ELEMS 1024     // elems per scan block (256 thr x 4)
#define SCAN_SHIFT 10

// ---------- fallback: direct atomic scatter-add (verified round 1) ----------
__global__ __launch_bounds__(256) void k_atomic_scatter(
    const float* __restrict__ x, const int* __restrict__ src,
    const int* __restrict__ tgt, float* __restrict__ out, int n_edges)
{
    const int lane = threadIdx.x & 63;
    const int wave = threadIdx.x >> 6;
    const int e = blockIdx.x * 4 + wave;
    if (e >= n_edges) return;
    const float v = x[(long long)src[e] * D_FEAT + lane];
    atomicAdd(&out[(long long)tgt[e] * D_FEAT + lane], v);
}

// ---------- software grid barrier (all blocks co-resident by construction) ----------
__device__ __forceinline__ void grid_barrier(int* bar, int target)
{
    __syncthreads();
    if (threadIdx.x == 0) {
        __threadfence();   // release prior writes to device scope
        __hip_atomic_fetch_add(bar, 1, __ATOMIC_RELEASE, __HIP_MEMORY_SCOPE_AGENT);
        while (__hip_atomic_load(bar, __ATOMIC_ACQUIRE, __HIP_MEMORY_SCOPE_AGENT) < target)
            __builtin_amdgcn_s_sleep(2);
        __threadfence();
    }
    __syncthreads();
}

// ---------- fused prep: convert + count + scan + scatter(from LDS) + sort ----------
// G = NBINS blocks, 256 threads. Requires NBLK <= G, nScan <= G, nScan <= 1024.
__global__ __launch_bounds__(256) void k_prep_coop(
    const float* __restrict__ x, unsigned short* __restrict__ xb, int n4,
    const int* __restrict__ src, const int* __restrict__ tgt,
    int* __restrict__ cnt, int* __restrict__ off, int* __restrict__ bsum,
    int* __restrict__ binned, int* __restrict__ srcSorted, int* __restrict__ nodeOff,
    int* __restrict__ bar,
    int E, int N, int NBINS, int NBLK, int nScan, int G)
{
    __shared__ unsigned int   ec_packed[CH];   // 16 KB: (src<<7)|tloc
    __shared__ unsigned short ec_bin[CH];      //  8 KB: bin id
    __shared__ int sh[NBINS_MAX];              //  4 KB: phase1 hist / phase3 ofs
    __shared__ int lds256[256];                //  1 KB: scans
    __shared__ int h128[SUBN], o128[SUBN];     //  1 KB: phase4 sort

    const int tid = threadIdx.x;
    const int b = blockIdx.x;

    // ---- phase 1: bf16 convert (grid-stride) + chunk count + LDS edge cache ----
    {
        const int stride = G * 256;
        for (int i = b * 256 + tid; i < n4; i += stride) {
            float4 f = ((const float4*)x)[i];
            ushort4 u; unsigned int w;
            w = __float_as_uint(f.x); u.x = (unsigned short)((w + 0x7fffu + ((w >> 16) & 1u)) >> 16);
            w = __float_as_uint(f.y); u.y = (unsigned short)((w + 0x7fffu + ((w >> 16) & 1u)) >> 16);
            w = __float_as_uint(f.z); u.z = (unsigned short)((w + 0x7fffu + ((w >> 16) & 1u)) >> 16);
            w = __float_as_uint(f.w); u.w = (unsigned short)((w + 0x7fffu + ((w >> 16) & 1u)) >> 16);
            ((ushort4*)xb)[i] = u;
        }
        if (b < NBLK) {
            for (int i = tid; i < NBINS; i += 256) sh[i] = 0;
            __syncthreads();
            const int base = b * CH;
            const int lim = min(E, base + CH);
            for (int e = base + tid; e < lim; e += 256) {
                int t = tgt[e];
                int s = src[e];
                int bin = t >> SUBN_SHIFT;
                ec_packed[e - base] = ((unsigned int)s << SUBN_SHIFT) | (unsigned int)(t & (SUBN - 1));
                ec_bin[e - base] = (unsigned short)bin;
                atomicAdd(&sh[bin], 1);
            }
            __syncthreads();
            for (int i = tid; i < NBINS; i += 256) cnt[(size_t)b * NBINS + i] = sh[i];
        }
    }
    grid_barrier(bar, G);

    // ---- phase 2a: partial exclusive scan in bin-major order (transposed read) ----
    if (b < nScan) {
        const int base = b * SCAN_ELEMS + tid * 4;
        const int M = NBLK * NBINS;
        int v[4];
#pragma unroll
        for (int k = 0; k < 4; ++k) {
            int i = base + k;
            if (i < M) {
                int bin = i / NBLK;
                int blk = i - bin * NBLK;
                v[k] = cnt[(size_t)blk * NBINS + bin];
            } else v[k] = 0;
        }
        const int tsum = v[0] + v[1] + v[2] + v[3];
        int val = tsum;
        lds256[tid] = val;
        __syncthreads();
        for (int d = 1; d < 256; d <<= 1) {
            int add = (tid >= d) ? lds256[tid - d] : 0;
            __syncthreads();
            val += add;
            lds256[tid] = val;
            __syncthreads();
        }
        if (tid == 255) bsum[b] = val;
        int p = val - tsum;
#pragma unroll
        for (int k = 0; k < 4; ++k) {
            int i = base + k;
            if (i < M) { off[i] = p; p += v[k]; }
        }
    }
    grid_barrier(bar, 2 * G);

    // ---- phase 2b: block 0 scans bsum[nScan] (256 thr x 4) ----
    if (b == 0) {
        const int base4 = tid * 4;
        int v[4];
#pragma unroll
        for (int k = 0; k < 4; ++k)
            v[k] = (base4 + k < nScan) ? bsum[base4 + k] : 0;
        const int tsum = v[0] + v[1] + v[2] + v[3];
        int val = tsum;
        lds256[tid] = val;
        __syncthreads();
        for (int d = 1; d < 256; d <<= 1) {
            int add = (tid >= d) ? lds256[tid - d] : 0;
            __syncthreads();
            val += add;
            lds256[tid] = val;
            __syncthreads();
        }
        int p = val - tsum;
#pragma unroll
        for (int k = 0; k < 4; ++k) {
            if (base4 + k < nScan) { bsum[base4 + k] = p; p += v[k]; }
        }
    }
    grid_barrier(bar, 3 * G);

    // ---- phase 3: scatter from LDS edge cache (no global edge re-read) ----
    if (b < NBLK) {
        for (int i = tid; i < NBINS; i += 256) {
            size_t idx = (size_t)i * NBLK + b;
            sh[i] = off[idx] + bsum[idx >> SCAN_SHIFT];
        }
        __syncthreads();
        const int base = b * CH;
        const int nloc = min(E, base + CH) - base;
        for (int i = tid; i < nloc; i += 256) {
            int bin = ec_bin[i];
            int p = atomicAdd(&sh[bin], 1);
            binned[p] = (int)ec_packed[i];
        }
    }
    grid_barrier(bar, 4 * G);

    // ---- phase 4: per-bin 128-bucket sort -> exact CSR ----
    if (b < NBINS) {
        const int bin = b;
        const size_t i0 = (size_t)bin * NBLK;
        const int binStart = off[i0] + bsum[i0 >> SCAN_SHIFT];
        int binEnd;
        if (bin + 1 < NBINS) {
            const size_t i1 = (size_t)(bin + 1) * NBLK;
            binEnd = off[i1] + bsum[i1 >> SCAN_SHIFT];
        } else binEnd = E;
        if (tid < SUBN) h128[tid] = 0;
        __syncthreads();
        for (int e = binStart + tid; e < binEnd; e += 256)
            atomicAdd(&h128[binned[e] & (SUBN - 1)], 1);
        __syncthreads();
        int orig = (tid < SUBN) ? h128[tid] : 0;
        int val = orig;
        if (tid < SUBN) o128[tid] = val;
        __syncthreads();
        for (int d = 1; d < SUBN; d <<= 1) {
            int add = (tid >= d && tid < SUBN) ? o128[tid - d] : 0;
            __syncthreads();
            if (tid < SUBN) { val += add; o128[tid] = val; }
            __syncthreads();
        }
        if (tid < SUBN) {
            int abs0 = binStart + (val - orig);
            o128[tid] = abs0;
            int node = bin * SUBN + tid;
            if (node < N) nodeOff[node] = abs0;
        }
        if (bin == 0 && tid == 0) nodeOff[N] = E;
        __syncthreads();
        for (int e = binStart + tid; e < binEnd; e += 256) {
            int entry = binned[e];
            int p = atomicAdd(&o128[entry & (SUBN - 1)], 1);
            srcSorted[p] = entry >> SUBN_SHIFT;
        }
    }
}

// ---------- gather: half-wave per row, degree-matched MLP ladder, grid-stride ----------
__global__ __launch_bounds__(256) void k_gather_bf2(
    const unsigned short* __restrict__ xb, const int* __restrict__ srcSorted,
    const int* __restrict__ nodeOff, float* __restrict__ out, int N)
{
    const int lane = threadIdx.x & 63;
    const int wave = threadIdx.x >> 6;
    const int half = lane >> 5;
    const int hl = lane & 31;
    const int wid0 = blockIdx.x * 4 + wave;
    const int wstride = gridDim.x * 4;

    for (int v = wid0; v < N; v += wstride) {
        const int start = __builtin_amdgcn_readfirstlane(nodeOff[v]);
        const int end   = __builtin_amdgcn_readfirstlane(nodeOff[v + 1]);
        float acc0 = 0.f, acc1 = 0.f;
        int k = start;
        for (; k + 16 <= end; k += 16) {
            int s[8]; unsigned int u[8];
#pragma unroll
            for (int j = 0; j < 8; ++j) s[j] = srcSorted[k + 2 * j + half];
#pragma unroll
            for (int j = 0; j < 8; ++j)
                u[j] = *(const unsigned int*)(xb + (size_t)s[j] * D_FEAT + 2 * hl);
#pragma unroll
            for (int j = 0; j < 8; ++j) {
                acc0 += __uint_as_float(u[j] << 16);
                acc1 += __uint_as_float(u[j] & 0xffff0000u);
            }
        }
        if (k + 8 <= end) {
            int s[4]; unsigned int u[4];
#pragma unroll
            for (int j = 0; j < 4; ++j) s[j] = srcSorted[k + 2 * j + half];
#pragma unroll
            for (int j = 0; j < 4; ++j)
                u[j] = *(const unsigned int*)(xb + (size_t)s[j] * D_FEAT + 2 * hl);
#pragma unroll
            for (int j = 0; j < 4; ++j) {
                acc0 += __uint_as_float(u[j] << 16);
                acc1 += __uint_as_float(u[j] & 0xffff0000u);
            }
            k += 8;
        }
        if (k + 4 <= end) {
            int s[2]; unsigned int u[2];
#pragma unroll
            for (int j = 0; j < 2; ++j) s[j] = srcSorted[k + 2 * j + half];
#pragma unroll
            for (int j = 0; j < 2; ++j)
                u[j] = *(const unsigned int*)(xb + (size_t)s[j] * D_FEAT + 2 * hl);
#pragma unroll
            for (int j = 0; j < 2; ++j) {
                acc0 += __uint_as_float(u[j] << 16);
                acc1 += __uint_as_float(u[j] & 0xffff0000u);
            }
            k += 4;
        }
        for (; k < end; k += 2) {
            int e = k + half;
            unsigned int u = 0;
            if (e < end)
                u = *(const unsigned int*)(xb + (size_t)srcSorted[e] * D_FEAT + 2 * hl);
            acc0 += __uint_as_float(u << 16);
            acc1 += __uint_as_float(u & 0xffff0000u);
        }
        acc0 += __shfl_xor(acc0, 32, 64);
        acc1 += __shfl_xor(acc1, 32, 64);
        if (half == 0)
            *(float2*)(out + (size_t)v * D_FEAT + 2 * hl) = make_float2(acc0, acc1);
    }
}

static inline size_t xbf_pad(int N) {
    return ((size_t)N * D_FEAT * 2 + 255) & ~(size_t)255;
}

extern "C" void kernel_launch(void* const* d_in, const int* in_sizes, int n_in,
                              void* d_out, int out_size, void* d_ws, size_t ws_size,
                              hipStream_t stream)
{
    const float* x  = (const float*)d_in[0];
    const int*   ei = (const int*)d_in[1];     // [2, E] flat int32
    const int E = in_sizes[1] / 2;
    const int N = out_size / D_FEAT;
    const int* src = ei;                        // edge_index[0] = source (gather)
    const int* tgt = ei + E;                    // edge_index[1] = target (scatter)
    float* out = (float*)d_out;

    const int NBINS = (N + SUBN - 1) / SUBN;                 // 782
    const int NBLK  = (E + CH - 1) / CH;                     // 391
    const long long M = (long long)NBLK * NBINS;             // 305,762
    const int nScan = (int)((M + SCAN_ELEMS - 1) / SCAN_ELEMS); // 299
    const int n4 = N * D_FEAT / 4;

    // ws layout: bar(256B) | xbf | cnt[M] | off[M] | bsum[1024] | binned[E] | srcSorted[E] | nodeOff[N+1]
    const size_t need = 256 + xbf_pad(N) +
        ((size_t)2 * M + 1024 + 2 * (size_t)E + N + 1) * sizeof(int);

    // guards: LDS-coresidency + phase coverage (NBLK,nScan <= G=NBINS; nScan <= 1024)
    if (need > ws_size || NBINS > NBINS_MAX || NBLK > NBINS || nScan > NBINS ||
        nScan > 1024 || (long long)N * SUBN >= (1LL << 31)) {
        hipMemsetAsync(d_out, 0, (size_t)out_size * sizeof(float), stream);
        k_atomic_scatter<<<(E + 3) / 4, 256, 0, stream>>>(x, src, tgt, out, E);
        return;
    }

    int* bar = (int*)d_ws;
    unsigned short* xbf = (unsigned short*)((char*)d_ws + 256);
    int* cnt = (int*)((char*)xbf + xbf_pad(N));
    int* off = cnt + M;
    int* bsum = off + M;
    int* binned = bsum + 1024;
    int* srcSorted = binned + E;
    int* nodeOff = srcSorted + E;

    hipMemsetAsync(bar, 0, sizeof(int), stream);
    k_prep_coop<<<NBINS, 256, 0, stream>>>(x, xbf, n4, src, tgt,
                                           cnt, off, bsum, binned, srcSorted, nodeOff,
                                           bar, E, N, NBINS, NBLK, nScan, NBINS);
    k_gather_bf2<<<2048, 256, 0, stream>>>(xbf, srcSorted, nodeOff, out, N);
}

// Round 18
// 88.939 us; speedup vs baseline: 7.1864x; 7.1864x over previous
//
#include <hip/hip_runtime.h>

#define D_FEAT 64
#define SUBN 256            // nodes per bin
#define SUBN_SHIFT 8
#define NBINS_MAX 1024
#define SCAN_BLOCK 256
#define SCAN_ELEMS 1024
#define SCAN_SHIFT 10

// ---------- fallback: direct atomic scatter-add (verified round 1) ----------
__global__ __launch_bounds__(256) void k_atomic_scatter(
    const float* __restrict__ x, const int* __restrict__ src,
    const int* __restrict__ tgt, float* __restrict__ out, int n_edges)
{
    const int lane = threadIdx.x & 63;
    const int wave = threadIdx.x >> 6;
    const int e = blockIdx.x * 4 + wave;
    if (e >= n_edges) return;
    const float v = x[(long long)src[e] * D_FEAT + lane];
    atomicAdd(&out[(long long)tgt[e] * D_FEAT + lane], v);
}

// ---------- helper: in-block exclusive scan of bsum[nScan<=1024] into bsumEx (LDS) ----------
__device__ __forceinline__ void block_scan_bsum(
    const int* __restrict__ bsum, int nScan, int* __restrict__ bsumEx, int* __restrict__ lds256)
{
    const int tid = threadIdx.x;
    const int base4 = tid * 4;
    int v[4];
#pragma unroll
    for (int k = 0; k < 4; ++k)
        v[k] = (base4 + k < nScan) ? bsum[base4 + k] : 0;
    const int tsum = v[0] + v[1] + v[2] + v[3];
    int val = tsum;
    lds256[tid] = val;
    __syncthreads();
    for (int d = 1; d < 256; d <<= 1) {
        int add = (tid >= d) ? lds256[tid - d] : 0;
        __syncthreads();
        val += add;
        lds256[tid] = val;
        __syncthreads();
    }
    int p = val - tsum;
#pragma unroll
    for (int k = 0; k < 4; ++k) {
        if (base4 + k < nScan) { bsumEx[base4 + k] = p; p += v[k]; }
    }
    __syncthreads();
}

// ---------- pass A1 (fused): x f32->bf16 convert (block-stride) + per-chunk bin histogram ----------
__global__ __launch_bounds__(256) void k_convert_count(
    const float* __restrict__ x, unsigned short* __restrict__ xb, int n4,
    const int* __restrict__ tgt, int* __restrict__ cnt, int E, int NBINS, int CH)
{
    __shared__ int c[NBINS_MAX];
    const int tid = threadIdx.x;
    const int stride = gridDim.x * 256;
    for (int i = blockIdx.x * 256 + tid; i < n4; i += stride) {
        float4 f = ((const float4*)x)[i];
        ushort4 u;
        unsigned int b;
        b = __float_as_uint(f.x); u.x = (unsigned short)((b + 0x7fffu + ((b >> 16) & 1u)) >> 16);
        b = __float_as_uint(f.y); u.y = (unsigned short)((b + 0x7fffu + ((b >> 16) & 1u)) >> 16);
        b = __float_as_uint(f.z); u.z = (unsigned short)((b + 0x7fffu + ((b >> 16) & 1u)) >> 16);
        b = __float_as_uint(f.w); u.w = (unsigned short)((b + 0x7fffu + ((b >> 16) & 1u)) >> 16);
        ((ushort4*)xb)[i] = u;
    }
    for (int i = tid; i < NBINS; i += 256) c[i] = 0;
    __syncthreads();
    const int base = blockIdx.x * CH;
    const int lim = min(E, base + CH);
    for (int e = base + tid; e < lim; e += 256)
        atomicAdd(&c[tgt[e] >> SUBN_SHIFT], 1);
    __syncthreads();
    for (int i = tid; i < NBINS; i += 256) cnt[(size_t)blockIdx.x * NBINS + i] = c[i];
}

// ---------- pass A2: partial exclusive scan in BIN-MAJOR order (transposed read) ----------
__global__ __launch_bounds__(SCAN_BLOCK) void k_scan_partial_T(
    const int* __restrict__ cnt, int* __restrict__ off,
    int* __restrict__ bsum, int M, int NBINS, int NBLK)
{
    __shared__ int lds[SCAN_BLOCK];
    const int tid = threadIdx.x;
    const int base = blockIdx.x * SCAN_ELEMS + tid * 4;
    int v[4];
#pragma unroll
    for (int k = 0; k < 4; ++k) {
        int i = base + k;
        if (i < M) {
            int bin = i / NBLK;
            int blk = i - bin * NBLK;
            v[k] = cnt[(size_t)blk * NBINS + bin];
        } else v[k] = 0;
    }
    const int tsum = v[0] + v[1] + v[2] + v[3];
    int val = tsum;
    lds[tid] = val;
    __syncthreads();
    for (int d = 1; d < SCAN_BLOCK; d <<= 1) {
        int add = (tid >= d) ? lds[tid - d] : 0;
        __syncthreads();
        val += add;
        lds[tid] = val;
        __syncthreads();
    }
    if (tid == SCAN_BLOCK - 1) bsum[blockIdx.x] = val;   // raw inclusive chunk total
    int p = val - tsum;
#pragma unroll
    for (int k = 0; k < 4; ++k) {
        int i = base + k;
        if (i < M) { off[i] = p; p += v[k]; }
    }
}

// ---------- pass A3: scatter edges into bin-grouped buffer (bsum scanned in-block) ----------
__global__ __launch_bounds__(256) void k_bin_scatter(
    const int* __restrict__ src, const int* __restrict__ tgt,
    const int* __restrict__ off, const int* __restrict__ bsum,
    int* __restrict__ binned, int E, int NBINS, int NBLK, int CH, int nScan)
{
    __shared__ int ofs[NBINS_MAX];
    __shared__ int bsumEx[1024];
    __shared__ int lds256[256];
    const int tid = threadIdx.x;
    const int b = blockIdx.x;
    block_scan_bsum(bsum, nScan, bsumEx, lds256);
    for (int i = tid; i < NBINS; i += 256) {
        size_t idx = (size_t)i * NBLK + b;
        ofs[i] = off[idx] + bsumEx[idx >> SCAN_SHIFT];
    }
    __syncthreads();
    const int base = b * CH;
    const int lim = min(E, base + CH);
    for (int e = base + tid; e < lim; e += 256) {
        int t = tgt[e];
        int s = src[e];
        int bin = t >> SUBN_SHIFT;
        int p = atomicAdd(&ofs[bin], 1);
        binned[p] = (s << SUBN_SHIFT) | (t & (SUBN - 1));   // pack src + local tgt (s<2^17 fits)
    }
}

// ---------- pass B: per-bin 256-bucket sort -> exact CSR (bsum scanned in-block) ----------
__global__ __launch_bounds__(256) void k_bin_sort(
    const int* __restrict__ binned, const int* __restrict__ off,
    const int* __restrict__ bsum,
    int* __restrict__ srcSorted, int* __restrict__ nodeOff,
    int E, int N, int NBLK, int NBINS, int nScan)
{
    __shared__ int bsumEx[1024];
    __shared__ int lds256[256];
    __shared__ int hist[SUBN];
    __shared__ int ofs[SUBN];
    const int tid = threadIdx.x;
    const int bin = blockIdx.x;
    block_scan_bsum(bsum, nScan, bsumEx, lds256);
    const size_t i0 = (size_t)bin * NBLK;
    const int binStart = off[i0] + bsumEx[i0 >> SCAN_SHIFT];
    int binEnd;
    if (bin + 1 < NBINS) {
        const size_t i1 = (size_t)(bin + 1) * NBLK;
        binEnd = off[i1] + bsumEx[i1 >> SCAN_SHIFT];
    } else binEnd = E;
    hist[tid] = 0;                         // SUBN == blockDim
    __syncthreads();
    for (int e = binStart + tid; e < binEnd; e += 256)
        atomicAdd(&hist[binned[e] & (SUBN - 1)], 1);
    __syncthreads();
    // exclusive scan of hist[256] (Hillis-Steele in LDS)
    int orig = hist[tid];
    int val = orig;
    ofs[tid] = val;
    __syncthreads();
    for (int d = 1; d < SUBN; d <<= 1) {
        int add = (tid >= d) ? ofs[tid - d] : 0;
        __syncthreads();
        val += add;
        ofs[tid] = val;
        __syncthreads();
    }
    {
        int abs0 = binStart + (val - orig);    // absolute exclusive start
        ofs[tid] = abs0;
        int node = bin * SUBN + tid;
        if (node < N) nodeOff[node] = abs0;
    }
    if (bin == 0 && tid == 0) nodeOff[N] = E;
    __syncthreads();
    for (int e = binStart + tid; e < binEnd; e += 256) {
        int entry = binned[e];
        int p = atomicAdd(&ofs[entry & (SUBN - 1)], 1);
        srcSorted[p] = entry >> SUBN_SHIFT;    // writes confined to this bin's window
    }
}

// ---------- pass C (bf16): half-wave per row, degree-matched MLP ladder, grid-stride ----------
__global__ __launch_bounds__(256) void k_gather_bf2(
    const unsigned short* __restrict__ xb, const int* __restrict__ srcSorted,
    const int* __restrict__ nodeOff, float* __restrict__ out, int N)
{
    const int lane = threadIdx.x & 63;
    const int wave = threadIdx.x >> 6;
    const int half = lane >> 5;
    const int hl = lane & 31;
    const int wid0 = blockIdx.x * 4 + wave;
    const int wstride = gridDim.x * 4;

    for (int v = wid0; v < N; v += wstride) {
        const int start = __builtin_amdgcn_readfirstlane(nodeOff[v]);
        const int end   = __builtin_amdgcn_readfirstlane(nodeOff[v + 1]);
        float acc0 = 0.f, acc1 = 0.f;
        int k = start;
        for (; k + 16 <= end; k += 16) {     // 8 row-loads in flight
            int s[8]; unsigned int u[8];
#pragma unroll
            for (int j = 0; j < 8; ++j) s[j] = srcSorted[k + 2 * j + half];
#pragma unroll
            for (int j = 0; j < 8; ++j)
                u[j] = *(const unsigned int*)(xb + (size_t)s[j] * D_FEAT + 2 * hl);
#pragma unroll
            for (int j = 0; j < 8; ++j) {
                acc0 += __uint_as_float(u[j] << 16);
                acc1 += __uint_as_float(u[j] & 0xffff0000u);
            }
        }
        if (k + 8 <= end) {
            int s[4]; unsigned int u[4];
#pragma unroll
            for (int j = 0; j < 4; ++j) s[j] = srcSorted[k + 2 * j + half];
#pragma unroll
            for (int j = 0; j < 4; ++j)
                u[j] = *(const unsigned int*)(xb + (size_t)s[j] * D_FEAT + 2 * hl);
#pragma unroll
            for (int j = 0; j < 4; ++j) {
                acc0 += __uint_as_float(u[j] << 16);
                acc1 += __uint_as_float(u[j] & 0xffff0000u);
            }
            k += 8;
        }
        if (k + 4 <= end) {
            int s[2]; unsigned int u[2];
#pragma unroll
            for (int j = 0; j < 2; ++j) s[j] = srcSorted[k + 2 * j + half];
#pragma unroll
            for (int j = 0; j < 2; ++j)
                u[j] = *(const unsigned int*)(xb + (size_t)s[j] * D_FEAT + 2 * hl);
#pragma unroll
            for (int j = 0; j < 2; ++j) {
                acc0 += __uint_as_float(u[j] << 16);
                acc1 += __uint_as_float(u[j] & 0xffff0000u);
            }
            k += 4;
        }
        for (; k < end; k += 2) {
            int e = k + half;
            unsigned int u = 0;
            if (e < end)
                u = *(const unsigned int*)(xb + (size_t)srcSorted[e] * D_FEAT + 2 * hl);
            acc0 += __uint_as_float(u << 16);
            acc1 += __uint_as_float(u & 0xffff0000u);
        }
        acc0 += __shfl_xor(acc0, 32, 64);
        acc1 += __shfl_xor(acc1, 32, 64);
        if (half == 0)
            *(float2*)(out + (size_t)v * D_FEAT + 2 * hl) = make_float2(acc0, acc1);
    }
}

// ---------- pass C (f32): fallback gather when ws can't hold xbf ----------
__global__ __launch_bounds__(256) void k_gather(
    const float* __restrict__ x, const int* __restrict__ srcSorted,
    const int* __restrict__ nodeOff, float* __restrict__ out, int N)
{
    const int lane = threadIdx.x & 63;
    const int wave = threadIdx.x >> 6;
    const int v = blockIdx.x * 4 + wave;
    if (v >= N) return;
    const int start = __builtin_amdgcn_readfirstlane(nodeOff[v]);
    const int end   = __builtin_amdgcn_readfirstlane(nodeOff[v + 1]);
    float acc = 0.f;
    int k = start;
    for (; k + 16 <= end; k += 16) {
        int s[16];
#pragma unroll
        for (int j = 0; j < 16; ++j) s[j] = srcSorted[k + j];
        float a[16];
#pragma unroll
        for (int j = 0; j < 16; ++j) a[j] = x[(size_t)s[j] * D_FEAT + lane];
        float t0 = (a[0]+a[1])+(a[2]+a[3]), t1 = (a[4]+a[5])+(a[6]+a[7]);
        float t2 = (a[8]+a[9])+(a[10]+a[11]), t3 = (a[12]+a[13])+(a[14]+a[15]);
        acc += (t0 + t1) + (t2 + t3);
    }
    for (; k < end; ++k)
        acc += x[(size_t)srcSorted[k] * D_FEAT + lane];
    out[(size_t)v * D_FEAT + lane] = acc;
}

static inline size_t xbf_pad(int N) {
    return ((size_t)N * D_FEAT * 2 + 255) & ~(size_t)255;
}
static inline size_t ws_need(long long M, int E, int N, int with_bf) {
    size_t b = ((size_t)2 * M + 1024 + 2 * (size_t)E + N + 1) * sizeof(int);
    if (with_bf) b += xbf_pad(N);
    return b;
}

extern "C" void kernel_launch(void* const* d_in, const int* in_sizes, int n_in,
                              void* d_out, int out_size, void* d_ws, size_t ws_size,
                              hipStream_t stream)
{
    const float* x  = (const float*)d_in[0];
    const int*   ei = (const int*)d_in[1];     // [2, E] flat int32
    const int E = in_sizes[1] / 2;
    const int N = out_size / D_FEAT;
    const int* src = ei;                        // edge_index[0] = source (gather)
    const int* tgt = ei + E;                    // edge_index[1] = target (scatter)
    float* out = (float*)d_out;

    const int NBINS = (N + SUBN - 1) / SUBN;                 // 391 for N=100K

    int CH = 0, NBLK = 0, USE_BF = 0; long long M = 0; int nScan = 0;
    const int ch_opts[3] = {4096, 8192, 16384};
    for (int bf = 1; bf >= 0 && CH == 0; --bf) {
        for (int c = 0; c < 3; ++c) {
            int ch = ch_opts[c];
            int nblk = (E + ch - 1) / ch;
            long long m = (long long)nblk * NBINS;
            int ns = (int)((m + SCAN_ELEMS - 1) / SCAN_ELEMS);
            if (ns <= 1024 && ws_need(m, E, N, bf) <= ws_size) {
                CH = ch; NBLK = nblk; M = m; nScan = ns; USE_BF = bf; break;
            }
        }
    }

    // packing needs (s << SUBN_SHIFT) to fit: N <= 2^(31-SUBN_SHIFT)
    if (CH == 0 || NBINS > NBINS_MAX || (long long)N >= (1LL << (31 - SUBN_SHIFT))) {
        hipMemsetAsync(d_out, 0, (size_t)out_size * sizeof(float), stream);
        k_atomic_scatter<<<(E + 3) / 4, 256, 0, stream>>>(x, src, tgt, out, E);
        return;
    }

    // layout: [xbf (256-B aligned)] | cnt[M] | off[M] | bsum[1024] | binned[E] | srcSorted[E] | nodeOff[N+1]
    unsigned short* xbf = (unsigned short*)d_ws;
    int* cnt = (int*)((char*)d_ws + (USE_BF ? xbf_pad(N) : 0));
    int* off = cnt + M;
    int* bsum = off + M;
    int* binned = bsum + 1024;
    int* srcSorted = binned + E;
    int* nodeOff = srcSorted + E;

    const int n4 = USE_BF ? (N * D_FEAT / 4) : 0;
    k_convert_count<<<NBLK, 256, 0, stream>>>(x, xbf, n4, tgt, cnt, E, NBINS, CH);
    k_scan_partial_T<<<nScan, SCAN_BLOCK, 0, stream>>>(cnt, off, bsum, (int)M, NBINS, NBLK);
    k_bin_scatter<<<NBLK, 256, 0, stream>>>(src, tgt, off, bsum, binned, E, NBINS, NBLK, CH, nScan);
    k_bin_sort<<<NBINS, 256, 0, stream>>>(binned, off, bsum, srcSorted, nodeOff, E, N, NBLK, NBINS, nScan);
    if (USE_BF)
        k_gather_bf2<<<2048, 256, 0, stream>>>(xbf, srcSorted, nodeOff, out, N);
    else
        k_gather<<<(N + 3) / 4, 256, 0, stream>>>(x, srcSorted, nodeOff, out, N);
}